// Round 2
// baseline (779.621 us; speedup 1.0000x reference)
//
#include <hip/hip_runtime.h>

#define B 8
#define C 64
#define N 4096
#define O 64
#define KNN 20
#define PQ 4
#define BN_EPS 1e-5f
#define NEG_SLOPE 0.2f

typedef _Float16 f16x8 __attribute__((ext_vector_type(8)));
typedef float    f32x4 __attribute__((ext_vector_type(4)));
#define MFMA16(a, b, c) __builtin_amdgcn_mfma_f32_16x16x32_f16(a, b, c, 0, 0, 0)

// insert (r,m) into ascending-sorted top-KNN list, dropping old min d[0].
// precondition: r > d[0]. Tie-safe (multiset semantics).
__device__ __forceinline__ void sorted_insert(float (&d)[KNN], int (&id)[KNN],
                                              float r, int m) {
    bool cp = true;
    #pragma unroll
    for (int j = 0; j < KNN - 1; ++j) {
        bool c = d[j + 1] < r;
        float nv = c ? d[j + 1] : (cp ? r : d[j]);
        int   ni = c ? id[j + 1] : (cp ? m : id[j]);
        d[j] = nv; id[j] = ni;
        cp = c;
    }
    d[KNN - 1]  = cp ? r : d[KNN - 1];
    id[KNN - 1] = cp ? m : id[KNN - 1];
}

// -------- K0: x (B,C,N) -> Xt (B,N,C) fp32, sq = ||x_n||^2, and AHL: f16 hi/lo
// frag-major: per 16-row group (4096 B): [term][khalf][quad][slot16][8 f16]
__global__ __launch_bounds__(256) void k_transpose(const float* __restrict__ x,
                                                   float* __restrict__ Xt,
                                                   float* __restrict__ sq,
                                                   char* __restrict__ AHL) {
    __shared__ float lds[C][65];
    int b    = blockIdx.x >> 6;
    int n0   = (blockIdx.x & 63) << 6;
    int lane = threadIdx.x & 63;
    int w    = threadIdx.x >> 6;
    #pragma unroll
    for (int i = 0; i < 16; ++i) {
        int c = w * 16 + i;
        lds[c][lane] = x[(size_t)b * C * N + (size_t)c * N + n0 + lane];
    }
    __syncthreads();
    #pragma unroll
    for (int i = 0; i < 16; ++i) {
        int nl = w * 16 + i;
        Xt[(size_t)b * N * C + (size_t)(n0 + nl) * C + lane] = lds[lane][nl];
    }
    // sq via quad-partial reduce: thread t owns n=t>>2, c-range (t&3)*16..+16.
    // 16 fma + 2 shfl per thread (was: 6 shfl per element = 96 DS-ops/thread).
    {
        int n_loc = threadIdx.x >> 2;
        int cg    = threadIdx.x & 3;
        float s = 0.f;
        #pragma unroll
        for (int ii = 0; ii < 16; ++ii) {
            float v = lds[cg * 16 + ii][n_loc];
            s = fmaf(v, v, s);
        }
        s += __shfl_xor(s, 1, 64);
        s += __shfl_xor(s, 2, 64);
        if (cg == 0) sq[b * N + n0 + n_loc] = s;
    }
    int s2  = threadIdx.x & 15;
    int rem = threadIdx.x >> 4;
    int qd  = rem & 3;
    int hh  = (rem >> 2) & 1;
    int tt  = rem >> 3;
    int kb  = hh * 32 + qd * 8;
    for (int i = 0; i < 4; ++i) {
        int rowl = i * 16 + s2;
        f16x8 pk;
        #pragma unroll
        for (int ii = 0; ii < 8; ++ii) {
            float v = lds[kb + ii][rowl];
            _Float16 hv = (_Float16)v;
            if (tt) hv = (_Float16)(v - (float)hv);
            pk[ii] = hv;
        }
        char* dst = AHL + ((size_t)b << 20) + (size_t)((n0 >> 4) + i) * 4096
                  + tt * 2048 + hh * 1024 + qd * 256 + s2 * 16;
        *(f16x8*)dst = pk;
    }
}

// -------- K1: a = X*(W1-W2)^T, bvec = X*W2^T
__global__ __launch_bounds__(256, 2) void k_ab(const float* __restrict__ Xt,
                                               const float* __restrict__ W,
                                               float* __restrict__ av,
                                               float* __restrict__ bv) {
    int b  = blockIdx.x >> 5;
    int n0 = (blockIdx.x & 31) << 7;
    int o  = threadIdx.x & 63;
    int w  = __builtin_amdgcn_readfirstlane((int)(threadIdx.x >> 6));
    float wa[C], wb[C];
    #pragma unroll
    for (int c = 0; c < C; ++c) {
        float w1 = W[o * 2 * C + c];
        float w2 = W[o * 2 * C + C + c];
        wa[c] = w1 - w2;
        wb[c] = w2;
    }
    const float* xb = Xt + (size_t)b * N * C;
    for (int i = 0; i < 32; ++i) {
        int n = n0 + w * 32 + i;
        const float4* xr4 = (const float4*)(xb + (size_t)n * C);
        float aa = 0.f, bb = 0.f;
        #pragma unroll
        for (int c4 = 0; c4 < C / 4; ++c4) {
            float4 xv = xr4[c4];
            aa = fmaf(xv.x, wa[c4 * 4 + 0], aa);
            bb = fmaf(xv.x, wb[c4 * 4 + 0], bb);
            aa = fmaf(xv.y, wa[c4 * 4 + 1], aa);
            bb = fmaf(xv.y, wb[c4 * 4 + 1], bb);
            aa = fmaf(xv.z, wa[c4 * 4 + 2], aa);
            bb = fmaf(xv.z, wb[c4 * 4 + 2], bb);
            aa = fmaf(xv.w, wa[c4 * 4 + 3], aa);
            bb = fmaf(xv.w, wb[c4 * 4 + 3], bb);
        }
        size_t oidx = ((size_t)b * N + n) * O + o;
        av[oidx] = aa;
        bv[oidx] = bb;
    }
}

// -------- K2: barrier-free streaming MFMA kNN. Zero LDS, zero __syncthreads.
// ONE WAVE PER BLOCK (grid 4096): no intra-block coupling exists, so 1-wave
// workgroups let the CU host up to 16 independent waves (vs 8 observed with
// 4-wave blocks) -> hides the sorted_insert dependent-chain latency.
// bid = qg*16 + b*2 + h (XCD swizzle: each XCD still sees 2 (b,h) streams).
// Wave owns queries qg*16..+16; lane quad q scans cand slice q.
//  - warm-fill: first 20 cands/lane fill slots directly, one bubble sort.
//  - shared quad threshold thr = max over the 4 quad-lanes of d[0].
__global__ __launch_bounds__(64, 4) void k_knn(const char* __restrict__ AHL,
                                               const float* __restrict__ sq,
                                               float* __restrict__ pdg,
                                               int* __restrict__ pig) {
    int bid  = blockIdx.x;
    int qg   = bid >> 4;
    int b    = (bid >> 1) & 7;
    int h    = bid & 1;
    int lane = threadIdx.x & 63;
    int quad = lane >> 4;
    const char*  AHLb = AHL + ((size_t)b << 20);
    const float* sqb  = sq + b * N;
    int cbase0 = h * (N / 2);
    const char* Asrc = AHLb + (size_t)cbase0 * 256;

    // B-frags: this wave's query group qg: hi/lo x khalf (16 VGPRs)
    const char* qb = AHLb + (size_t)qg * 4096 + lane * 16;
    f16x8 bh0 = *(const f16x8*)(qb);
    f16x8 bh1 = *(const f16x8*)(qb + 1024);
    f16x8 bl0 = *(const f16x8*)(qb + 2048);
    f16x8 bl1 = *(const f16x8*)(qb + 3072);

    float d[KNN]; int id[KNN];
    float pv[PQ]; int pi[PQ]; int pc = 0;
    #pragma unroll
    for (int j = 0; j < PQ; ++j) { pv[j] = 0.f; pi[j] = 0; }

    // prefetch iter 0
    const char* p0 = Asrc + lane * 16;
    f16x8 na0 = *(const f16x8*)(p0);
    f16x8 na1 = *(const f16x8*)(p0 + 1024);
    f16x8 na2 = *(const f16x8*)(p0 + 2048);
    f16x8 na3 = *(const f16x8*)(p0 + 3072);
    float4 nsq = *(const float4*)(sqb + cbase0 + quad * 4);

    // ---- warm-fill: iters 0..4 (20 cands per lane) fill all KNN slots
    #pragma unroll
    for (int it = 0; it < 5; ++it) {
        f16x8 a0 = na0, a1 = na1, a2 = na2, a3 = na3;
        float4 sqv = nsq;
        {
            const char* p = Asrc + (size_t)(it + 1) * 4096 + lane * 16;
            na0 = *(const f16x8*)(p);
            na1 = *(const f16x8*)(p + 1024);
            na2 = *(const f16x8*)(p + 2048);
            na3 = *(const f16x8*)(p + 3072);
            nsq = *(const float4*)(sqb + cbase0 + (it + 1) * 16 + quad * 4);
        }
        f32x4 acc = {0.f, 0.f, 0.f, 0.f};
        acc = MFMA16(a0, bh0, acc);
        acc = MFMA16(a1, bh1, acc);
        acc = MFMA16(a0, bl0, acc);
        acc = MFMA16(a1, bl1, acc);
        acc = MFMA16(a2, bh0, acc);
        acc = MFMA16(a3, bh1, acc);
        int c0 = cbase0 + it * 16 + quad * 4;
        #pragma unroll
        for (int r = 0; r < 4; ++r) {
            float sc = fmaf(2.f, acc[r],
                            -((r == 0) ? sqv.x : (r == 1) ? sqv.y
                                       : (r == 2) ? sqv.z : sqv.w));
            d[it * 4 + r]  = sc;          // compile-time slot index
            id[it * 4 + r] = c0 + r;
        }
    }
    // one-time in-register bubble sort, ascending (compile-time indices)
    #pragma unroll
    for (int i = 0; i < KNN - 1; ++i) {
        #pragma unroll
        for (int j = 0; j < KNN - 1 - i; ++j) {
            bool sw = d[j] > d[j + 1];
            float tv = d[j]; int ti = id[j];
            d[j]      = sw ? d[j + 1] : d[j];
            id[j]     = sw ? id[j + 1] : id[j];
            d[j + 1]  = sw ? tv : d[j + 1];
            id[j + 1] = sw ? ti : id[j + 1];
        }
    }
    // shared threshold across the 4 quad-lanes serving this query
    float thr = d[0];
    thr = fmaxf(thr, __shfl_xor(thr, 16, 64));
    thr = fmaxf(thr, __shfl_xor(thr, 32, 64));

    #pragma unroll 1
    for (int it = 5; it < 128; ++it) {         // 16 cands per iter
        f16x8 a0 = na0, a1 = na1, a2 = na2, a3 = na3;
        float4 sqv = nsq;
        if (it + 1 < 128) {                    // issue next-iter loads early
            const char* p = Asrc + (size_t)(it + 1) * 4096 + lane * 16;
            na0 = *(const f16x8*)(p);
            na1 = *(const f16x8*)(p + 1024);
            na2 = *(const f16x8*)(p + 2048);
            na3 = *(const f16x8*)(p + 3072);
            nsq = *(const float4*)(sqb + cbase0 + (it + 1) * 16 + quad * 4);
        }
        f32x4 acc = {0.f, 0.f, 0.f, 0.f};
        acc = MFMA16(a0, bh0, acc);
        acc = MFMA16(a1, bh1, acc);
        acc = MFMA16(a0, bl0, acc);
        acc = MFMA16(a1, bl1, acc);
        acc = MFMA16(a2, bh0, acc);
        acc = MFMA16(a3, bh1, acc);
        int c0 = cbase0 + it * 16 + quad * 4;  // lane's 4 cands (row=quad*4+r)
        #pragma unroll
        for (int r = 0; r < 4; ++r) {
            float sc = fmaf(2.f, acc[r],
                            -((r == 0) ? sqv.x : (r == 1) ? sqv.y
                                       : (r == 2) ? sqv.z : sqv.w));
            if (sc > thr) {                    // global-ish filter, rare pass
                #pragma unroll
                for (int j = 0; j < PQ; ++j) {
                    bool sel = (pc == j);
                    pv[j] = sel ? sc : pv[j];
                    pi[j] = sel ? (c0 + r) : pi[j];
                }
                ++pc;
            }
            if (__any(pc == PQ)) {             // drain all lanes in parallel
                #pragma unroll
                for (int j = 0; j < PQ; ++j)
                    if (j < pc && pv[j] > d[0]) sorted_insert(d, id, pv[j], pi[j]);
                pc = 0;
                float t = d[0];                // refresh shared threshold
                t = fmaxf(t, __shfl_xor(t, 16, 64));
                t = fmaxf(t, __shfl_xor(t, 32, 64));
                thr = fmaxf(thr, t);
            }
        }
    }
    #pragma unroll
    for (int j = 0; j < PQ; ++j)               // final flush
        if (j < pc && pv[j] > d[0]) sorted_insert(d, id, pv[j], pi[j]);

    // in-wave quad-merge tournament via shuffles: 2,3 -> 0,1 then 1 -> 0
    #pragma unroll 1
    for (int step = 0; step < 2; ++step) {
        int off = (step == 0) ? 32 : 16;
        bool active = (step == 0) ? (quad < 2) : (quad == 0);
        for (int j = KNN - 1; j >= 0; --j) {   // descending; early-exit
            float rv = __shfl(d[j], lane + off, 64);
            int   ri = __shfl(id[j], lane + off, 64);
            bool ins = active && (rv > d[0]);
            if (!__any(ins)) break;
            if (ins) sorted_insert(d, id, rv, ri);
        }
    }
    if (lane < 16) {
        size_t rr = (size_t)b * N + qg * 16 + lane;
        float* po = pdg + (rr * 2 + h) * KNN;
        int*   qo = pig + (rr * 2 + h) * KNN;
        #pragma unroll
        for (int j = 0; j < KNN; ++j) { po[j] = d[j]; qo[j] = id[j]; }
    }
}

// -------- K2b: merge the 2 sorted half-lists per query -> knn indices
__global__ __launch_bounds__(128) void k_merge(const float* __restrict__ pdg,
                                               const int* __restrict__ pig,
                                               int* __restrict__ knn) {
    __shared__ float sd[128][41];
    __shared__ int   si[128][41];
    int t = threadIdx.x;
    size_t rr = (size_t)blockIdx.x * 128 + t;
    const float* pr = pdg + rr * (2 * KNN);
    const int*   qr = pig + rr * (2 * KNN);
    #pragma unroll
    for (int j = 0; j < 2 * KNN; ++j) { sd[t][j] = pr[j]; si[t][j] = qr[j]; }
    int i = KNN - 1, j = KNN - 1;
    int* op = knn + rr * KNN;
    for (int o = 0; o < KNN; ++o) {
        bool t0 = (j < 0) || (i >= 0 && sd[t][i] >= sd[t][KNN + j]);
        op[o] = t0 ? si[t][i] : si[t][KNN + j];
        if (t0) --i; else --j;
    }
}

// -------- K3: out[b][o][n] = leaky(scale*(a[n][o] + max_k bvec[idx_k][o]) + bias)
__global__ __launch_bounds__(256) void k_out(const float* __restrict__ av,
                                             const float* __restrict__ bv,
                                             const int* __restrict__ knn,
                                             const float* __restrict__ gamma,
                                             const float* __restrict__ beta,
                                             const float* __restrict__ rmean,
                                             const float* __restrict__ rvar,
                                             float* __restrict__ out) {
    __shared__ float lds[64][65];
    int b    = blockIdx.x >> 6;
    int n0   = (blockIdx.x & 63) << 6;
    int lane = threadIdx.x & 63;
    int w    = __builtin_amdgcn_readfirstlane((int)(threadIdx.x >> 6));
    int o    = lane;
    float scale = gamma[o] * rsqrtf(rvar[o] + BN_EPS);
    float bias  = fmaf(-rmean[o], scale, beta[o]);
    const float* bvb = bv + (size_t)b * N * O;
    for (int i = 0; i < 16; ++i) {
        int n = n0 + w * 16 + i;
        const int* kn = knn + ((size_t)b * N + n) * KNN;
        float mx = -3.4e38f, mn = 3.4e38f;
        #pragma unroll
        for (int j = 0; j < KNN; ++j) {
            float v = bvb[(size_t)kn[j] * O + o];
            mx = fmaxf(mx, v);
            mn = fminf(mn, v);
        }
        float a   = av[((size_t)b * N + n) * O + o];
        float sel = (scale >= 0.f) ? (a + mx) : (a + mn);
        float y   = fmaf(sel, scale, bias);
        y = fmaxf(y, NEG_SLOPE * y);
        lds[o][w * 16 + i] = y;
    }
    __syncthreads();
    int r  = threadIdx.x >> 2;
    int c0 = (threadIdx.x & 3) << 4;
    float* ob = out + (size_t)b * O * N + (size_t)r * N + n0;
    #pragma unroll
    for (int j = 0; j < 16; j += 4) {
        float4 v;
        v.x = lds[r][c0 + j + 0];
        v.y = lds[r][c0 + j + 1];
        v.z = lds[r][c0 + j + 2];
        v.w = lds[r][c0 + j + 3];
        *(float4*)(ob + c0 + j) = v;
    }
}

extern "C" void kernel_launch(void* const* d_in, const int* in_sizes, int n_in,
                              void* d_out, int out_size, void* d_ws, size_t ws_size,
                              hipStream_t stream) {
    const float* x     = (const float*)d_in[0];
    const float* W     = (const float*)d_in[1];
    const float* gamma = (const float*)d_in[2];
    const float* beta  = (const float*)d_in[3];
    const float* rmean = (const float*)d_in[4];
    const float* rvar  = (const float*)d_in[5];
    float* out = (float*)d_out;

    char* wsb = (char*)d_ws;
    float* Xt  = (float*)(wsb);                 //  8 MB
    float* sqn = (float*)(wsb + 8388608);       //  128 KB
    float* av  = (float*)(wsb + 8519680);       //  8 MB
    float* bvv = (float*)(wsb + 16908288);      //  8 MB
    int*   knn = (int*)  (wsb + 25296896);      //  2.5 MB
    char*  AHL =         (wsb + 27918336);      //  8 MB f16 hi/lo frag-major
    float* pdg = (float*)(wsb + 36306944);      //  5.24 MB partial dists
    int*   pig = (int*)  (wsb + 41549824);      //  5.24 MB partial ids

    k_transpose<<<512, 256, 0, stream>>>(x, Xt, sqn, AHL);
    k_ab<<<256, 256, 0, stream>>>(Xt, W, av, bvv);
    k_knn<<<4096, 64, 0, stream>>>(AHL, sqn, pdg, pig);
    k_merge<<<256, 128, 0, stream>>>(pdg, pig, knn);
    k_out<<<512, 256, 0, stream>>>(av, bvv, knn, gamma, beta, rmean, rvar, out);
}

// Round 3
// 380.162 us; speedup vs baseline: 2.0508x; 2.0508x over previous
//
#include <hip/hip_runtime.h>

#define B 8
#define C 64
#define N 4096
#define O 64
#define KNN 20
#define PQ 4
#define BN_EPS 1e-5f
#define NEG_SLOPE 0.2f

typedef _Float16 f16x8 __attribute__((ext_vector_type(8)));
typedef float    f32x4 __attribute__((ext_vector_type(4)));
#define MFMA16(a, b, c) __builtin_amdgcn_mfma_f32_16x16x32_f16(a, b, c, 0, 0, 0)

// insert (r,m) into ascending-sorted top-KNN list, dropping old min d[0].
// precondition: r > d[0]. Tie-safe (insert below existing equal value).
// Branch-free parallel form: new_d[j] = med3(d[j], d[j+1], r) is exactly
// {shift below insertion point, r at insertion point, unchanged above}.
// Depth ~2 (vs 19-step chained shift) and ~77 instrs (vs ~114).
__device__ __forceinline__ void sorted_insert(float (&d)[KNN], int (&id)[KNN],
                                              float r, int m) {
    bool c[KNN];
    #pragma unroll
    for (int j = 0; j < KNN; ++j) c[j] = d[j] < r;
    #pragma unroll
    for (int j = 0; j < KNN - 1; ++j) {
        d[j]  = __builtin_amdgcn_fmed3f(d[j], d[j + 1], r);
        id[j] = c[j + 1] ? id[j + 1] : (c[j] ? m : id[j]);
    }
    d[KNN - 1]  = c[KNN - 1] ? r : d[KNN - 1];
    id[KNN - 1] = c[KNN - 1] ? m : id[KNN - 1];
}

// -------- K0: x (B,C,N) -> Xt (B,N,C) fp32, sq = ||x_n||^2, and AHL: f16 hi/lo
// frag-major: per 16-row group (4096 B): [term][khalf][quad][slot16][8 f16]
__global__ __launch_bounds__(256) void k_transpose(const float* __restrict__ x,
                                                   float* __restrict__ Xt,
                                                   float* __restrict__ sq,
                                                   char* __restrict__ AHL) {
    __shared__ float lds[C][65];
    int b    = blockIdx.x >> 6;
    int n0   = (blockIdx.x & 63) << 6;
    int lane = threadIdx.x & 63;
    int w    = threadIdx.x >> 6;
    #pragma unroll
    for (int i = 0; i < 16; ++i) {
        int c = w * 16 + i;
        lds[c][lane] = x[(size_t)b * C * N + (size_t)c * N + n0 + lane];
    }
    __syncthreads();
    #pragma unroll
    for (int i = 0; i < 16; ++i) {
        int nl = w * 16 + i;
        Xt[(size_t)b * N * C + (size_t)(n0 + nl) * C + lane] = lds[lane][nl];
    }
    // sq via quad-partial reduce: thread t owns n=t>>2, c-range (t&3)*16..+16.
    {
        int n_loc = threadIdx.x >> 2;
        int cg    = threadIdx.x & 3;
        float s = 0.f;
        #pragma unroll
        for (int ii = 0; ii < 16; ++ii) {
            float v = lds[cg * 16 + ii][n_loc];
            s = fmaf(v, v, s);
        }
        s += __shfl_xor(s, 1, 64);
        s += __shfl_xor(s, 2, 64);
        if (cg == 0) sq[b * N + n0 + n_loc] = s;
    }
    int s2  = threadIdx.x & 15;
    int rem = threadIdx.x >> 4;
    int qd  = rem & 3;
    int hh  = (rem >> 2) & 1;
    int tt  = rem >> 3;
    int kb  = hh * 32 + qd * 8;
    for (int i = 0; i < 4; ++i) {
        int rowl = i * 16 + s2;
        f16x8 pk;
        #pragma unroll
        for (int ii = 0; ii < 8; ++ii) {
            float v = lds[kb + ii][rowl];
            _Float16 hv = (_Float16)v;
            if (tt) hv = (_Float16)(v - (float)hv);
            pk[ii] = hv;
        }
        char* dst = AHL + ((size_t)b << 20) + (size_t)((n0 >> 4) + i) * 4096
                  + tt * 2048 + hh * 1024 + qd * 256 + s2 * 16;
        *(f16x8*)dst = pk;
    }
}

// -------- K1: a = X*(W1-W2)^T, bvec = X*W2^T
__global__ __launch_bounds__(256, 2) void k_ab(const float* __restrict__ Xt,
                                               const float* __restrict__ W,
                                               float* __restrict__ av,
                                               float* __restrict__ bv) {
    int b  = blockIdx.x >> 5;
    int n0 = (blockIdx.x & 31) << 7;
    int o  = threadIdx.x & 63;
    int w  = __builtin_amdgcn_readfirstlane((int)(threadIdx.x >> 6));
    float wa[C], wb[C];
    #pragma unroll
    for (int c = 0; c < C; ++c) {
        float w1 = W[o * 2 * C + c];
        float w2 = W[o * 2 * C + C + c];
        wa[c] = w1 - w2;
        wb[c] = w2;
    }
    const float* xb = Xt + (size_t)b * N * C;
    for (int i = 0; i < 32; ++i) {
        int n = n0 + w * 32 + i;
        const float4* xr4 = (const float4*)(xb + (size_t)n * C);
        float aa = 0.f, bb = 0.f;
        #pragma unroll
        for (int c4 = 0; c4 < C / 4; ++c4) {
            float4 xv = xr4[c4];
            aa = fmaf(xv.x, wa[c4 * 4 + 0], aa);
            bb = fmaf(xv.x, wb[c4 * 4 + 0], bb);
            aa = fmaf(xv.y, wa[c4 * 4 + 1], aa);
            bb = fmaf(xv.y, wb[c4 * 4 + 1], bb);
            aa = fmaf(xv.z, wa[c4 * 4 + 2], aa);
            bb = fmaf(xv.z, wb[c4 * 4 + 2], bb);
            aa = fmaf(xv.w, wa[c4 * 4 + 3], aa);
            bb = fmaf(xv.w, wb[c4 * 4 + 3], bb);
        }
        size_t oidx = ((size_t)b * N + n) * O + o;
        av[oidx] = aa;
        bv[oidx] = bb;
    }
}

// -------- K2: barrier-free streaming MFMA kNN. Zero LDS, zero __syncthreads.
// 4-wave blocks, grid 1024 (R2's 1-wave experiment spilled: launch_bounds
// (64,4) clamped VGPR to 64 -> d[]/id[] to scratch -> 1 GB WRITE_SIZE. Do not
// repeat without verifying kernel-resource-usage first.)
// bid = rb*16 + b*2 + h (XCD swizzle). Wave w owns queries rb*64 + w*16..+16;
// lane quad q scans cand slice q. Top-k fully in regs.
//  - warm-fill: first 20 cands/lane fill slots directly, one bubble sort.
//  - shared quad threshold thr = max over the 4 quad-lanes of d[0].
//  - med3 parallel insert (see sorted_insert).
__global__ __launch_bounds__(256, 3) void k_knn(const char* __restrict__ AHL,
                                                const float* __restrict__ sq,
                                                float* __restrict__ pdg,
                                                int* __restrict__ pig) {
    int bid  = blockIdx.x;
    int rb   = bid >> 4;
    int b    = (bid >> 1) & 7;
    int h    = bid & 1;
    int tid  = threadIdx.x;
    int lane = tid & 63;
    int w    = __builtin_amdgcn_readfirstlane(tid >> 6);
    int quad = lane >> 4;
    const char*  AHLb = AHL + ((size_t)b << 20);
    const float* sqb  = sq + b * N;
    int cbase0 = h * (N / 2);
    const char* Asrc = AHLb + (size_t)cbase0 * 256;

    // B-frags: this wave's query group (rb*4 + w): hi/lo x khalf (16 VGPRs)
    const char* qb = AHLb + (size_t)(rb * 4 + w) * 4096 + lane * 16;
    f16x8 bh0 = *(const f16x8*)(qb);
    f16x8 bh1 = *(const f16x8*)(qb + 1024);
    f16x8 bl0 = *(const f16x8*)(qb + 2048);
    f16x8 bl1 = *(const f16x8*)(qb + 3072);

    float d[KNN]; int id[KNN];
    float pv[PQ]; int pi[PQ]; int pc = 0;
    #pragma unroll
    for (int j = 0; j < PQ; ++j) { pv[j] = 0.f; pi[j] = 0; }

    // prefetch iter 0
    const char* p0 = Asrc + lane * 16;
    f16x8 na0 = *(const f16x8*)(p0);
    f16x8 na1 = *(const f16x8*)(p0 + 1024);
    f16x8 na2 = *(const f16x8*)(p0 + 2048);
    f16x8 na3 = *(const f16x8*)(p0 + 3072);
    float4 nsq = *(const float4*)(sqb + cbase0 + quad * 4);

    // ---- warm-fill: iters 0..4 (20 cands per lane) fill all KNN slots
    #pragma unroll
    for (int it = 0; it < 5; ++it) {
        f16x8 a0 = na0, a1 = na1, a2 = na2, a3 = na3;
        float4 sqv = nsq;
        {
            const char* p = Asrc + (size_t)(it + 1) * 4096 + lane * 16;
            na0 = *(const f16x8*)(p);
            na1 = *(const f16x8*)(p + 1024);
            na2 = *(const f16x8*)(p + 2048);
            na3 = *(const f16x8*)(p + 3072);
            nsq = *(const float4*)(sqb + cbase0 + (it + 1) * 16 + quad * 4);
        }
        f32x4 acc = {0.f, 0.f, 0.f, 0.f};
        acc = MFMA16(a0, bh0, acc);
        acc = MFMA16(a1, bh1, acc);
        acc = MFMA16(a0, bl0, acc);
        acc = MFMA16(a1, bl1, acc);
        acc = MFMA16(a2, bh0, acc);
        acc = MFMA16(a3, bh1, acc);
        int c0 = cbase0 + it * 16 + quad * 4;
        #pragma unroll
        for (int r = 0; r < 4; ++r) {
            float sc = fmaf(2.f, acc[r],
                            -((r == 0) ? sqv.x : (r == 1) ? sqv.y
                                       : (r == 2) ? sqv.z : sqv.w));
            d[it * 4 + r]  = sc;          // compile-time slot index
            id[it * 4 + r] = c0 + r;
        }
    }
    // one-time in-register bubble sort, ascending (compile-time indices)
    #pragma unroll
    for (int i = 0; i < KNN - 1; ++i) {
        #pragma unroll
        for (int j = 0; j < KNN - 1 - i; ++j) {
            bool sw = d[j] > d[j + 1];
            float tv = d[j]; int ti = id[j];
            d[j]      = sw ? d[j + 1] : d[j];
            id[j]     = sw ? id[j + 1] : id[j];
            d[j + 1]  = sw ? tv : d[j + 1];
            id[j + 1] = sw ? ti : id[j + 1];
        }
    }
    // shared threshold across the 4 quad-lanes serving this query
    float thr = d[0];
    thr = fmaxf(thr, __shfl_xor(thr, 16, 64));
    thr = fmaxf(thr, __shfl_xor(thr, 32, 64));

    #pragma unroll 1
    for (int it = 5; it < 128; ++it) {         // 16 cands per iter
        f16x8 a0 = na0, a1 = na1, a2 = na2, a3 = na3;
        float4 sqv = nsq;
        if (it + 1 < 128) {                    // issue next-iter loads early
            const char* p = Asrc + (size_t)(it + 1) * 4096 + lane * 16;
            na0 = *(const f16x8*)(p);
            na1 = *(const f16x8*)(p + 1024);
            na2 = *(const f16x8*)(p + 2048);
            na3 = *(const f16x8*)(p + 3072);
            nsq = *(const float4*)(sqb + cbase0 + (it + 1) * 16 + quad * 4);
        }
        f32x4 acc = {0.f, 0.f, 0.f, 0.f};
        acc = MFMA16(a0, bh0, acc);
        acc = MFMA16(a1, bh1, acc);
        acc = MFMA16(a0, bl0, acc);
        acc = MFMA16(a1, bl1, acc);
        acc = MFMA16(a2, bh0, acc);
        acc = MFMA16(a3, bh1, acc);
        int c0 = cbase0 + it * 16 + quad * 4;  // lane's 4 cands (row=quad*4+r)
        #pragma unroll
        for (int r = 0; r < 4; ++r) {
            float sc = fmaf(2.f, acc[r],
                            -((r == 0) ? sqv.x : (r == 1) ? sqv.y
                                       : (r == 2) ? sqv.z : sqv.w));
            if (sc > thr) {                    // global-ish filter, rare pass
                #pragma unroll
                for (int j = 0; j < PQ; ++j) {
                    bool sel = (pc == j);
                    pv[j] = sel ? sc : pv[j];
                    pi[j] = sel ? (c0 + r) : pi[j];
                }
                ++pc;
            }
            if (__any(pc == PQ)) {             // drain all lanes in parallel
                #pragma unroll
                for (int j = 0; j < PQ; ++j)
                    if (j < pc && pv[j] > d[0]) sorted_insert(d, id, pv[j], pi[j]);
                pc = 0;
                float t = d[0];                // refresh shared threshold
                t = fmaxf(t, __shfl_xor(t, 16, 64));
                t = fmaxf(t, __shfl_xor(t, 32, 64));
                thr = fmaxf(thr, t);
            }
        }
    }
    #pragma unroll
    for (int j = 0; j < PQ; ++j)               // final flush
        if (j < pc && pv[j] > d[0]) sorted_insert(d, id, pv[j], pi[j]);

    // in-wave quad-merge tournament via shuffles: 2,3 -> 0,1 then 1 -> 0
    #pragma unroll 1
    for (int step = 0; step < 2; ++step) {
        int off = (step == 0) ? 32 : 16;
        bool active = (step == 0) ? (quad < 2) : (quad == 0);
        for (int j = KNN - 1; j >= 0; --j) {   // descending; early-exit
            float rv = __shfl(d[j], lane + off, 64);
            int   ri = __shfl(id[j], lane + off, 64);
            bool ins = active && (rv > d[0]);
            if (!__any(ins)) break;
            if (ins) sorted_insert(d, id, rv, ri);
        }
    }
    if (lane < 16) {
        size_t rr = (size_t)b * N + rb * 64 + w * 16 + lane;
        float* po = pdg + (rr * 2 + h) * KNN;
        int*   qo = pig + (rr * 2 + h) * KNN;
        #pragma unroll
        for (int j = 0; j < KNN; ++j) { po[j] = d[j]; qo[j] = id[j]; }
    }
}

// -------- K2b: merge the 2 sorted half-lists per query -> knn indices
__global__ __launch_bounds__(128) void k_merge(const float* __restrict__ pdg,
                                               const int* __restrict__ pig,
                                               int* __restrict__ knn) {
    __shared__ float sd[128][41];
    __shared__ int   si[128][41];
    int t = threadIdx.x;
    size_t rr = (size_t)blockIdx.x * 128 + t;
    const float* pr = pdg + rr * (2 * KNN);
    const int*   qr = pig + rr * (2 * KNN);
    #pragma unroll
    for (int j = 0; j < 2 * KNN; ++j) { sd[t][j] = pr[j]; si[t][j] = qr[j]; }
    int i = KNN - 1, j = KNN - 1;
    int* op = knn + rr * KNN;
    for (int o = 0; o < KNN; ++o) {
        bool t0 = (j < 0) || (i >= 0 && sd[t][i] >= sd[t][KNN + j]);
        op[o] = t0 ? si[t][i] : si[t][KNN + j];
        if (t0) --i; else --j;
    }
}

// -------- K3: out[b][o][n] = leaky(scale*(a[n][o] + max_k bvec[idx_k][o]) + bias)
__global__ __launch_bounds__(256) void k_out(const float* __restrict__ av,
                                             const float* __restrict__ bv,
                                             const int* __restrict__ knn,
                                             const float* __restrict__ gamma,
                                             const float* __restrict__ beta,
                                             const float* __restrict__ rmean,
                                             const float* __restrict__ rvar,
                                             float* __restrict__ out) {
    __shared__ float lds[64][65];
    int b    = blockIdx.x >> 6;
    int n0   = (blockIdx.x & 63) << 6;
    int lane = threadIdx.x & 63;
    int w    = __builtin_amdgcn_readfirstlane((int)(threadIdx.x >> 6));
    int o    = lane;
    float scale = gamma[o] * rsqrtf(rvar[o] + BN_EPS);
    float bias  = fmaf(-rmean[o], scale, beta[o]);
    const float* bvb = bv + (size_t)b * N * O;
    for (int i = 0; i < 16; ++i) {
        int n = n0 + w * 16 + i;
        const int* kn = knn + ((size_t)b * N + n) * KNN;
        float mx = -3.4e38f, mn = 3.4e38f;
        #pragma unroll
        for (int j = 0; j < KNN; ++j) {
            float v = bvb[(size_t)kn[j] * O + o];
            mx = fmaxf(mx, v);
            mn = fminf(mn, v);
        }
        float a   = av[((size_t)b * N + n) * O + o];
        float sel = (scale >= 0.f) ? (a + mx) : (a + mn);
        float y   = fmaf(sel, scale, bias);
        y = fmaxf(y, NEG_SLOPE * y);
        lds[o][w * 16 + i] = y;
    }
    __syncthreads();
    int r  = threadIdx.x >> 2;
    int c0 = (threadIdx.x & 3) << 4;
    float* ob = out + (size_t)b * O * N + (size_t)r * N + n0;
    #pragma unroll
    for (int j = 0; j < 16; j += 4) {
        float4 v;
        v.x = lds[r][c0 + j + 0];
        v.y = lds[r][c0 + j + 1];
        v.z = lds[r][c0 + j + 2];
        v.w = lds[r][c0 + j + 3];
        *(float4*)(ob + c0 + j) = v;
    }
}

extern "C" void kernel_launch(void* const* d_in, const int* in_sizes, int n_in,
                              void* d_out, int out_size, void* d_ws, size_t ws_size,
                              hipStream_t stream) {
    const float* x     = (const float*)d_in[0];
    const float* W     = (const float*)d_in[1];
    const float* gamma = (const float*)d_in[2];
    const float* beta  = (const float*)d_in[3];
    const float* rmean = (const float*)d_in[4];
    const float* rvar  = (const float*)d_in[5];
    float* out = (float*)d_out;

    char* wsb = (char*)d_ws;
    float* Xt  = (float*)(wsb);                 //  8 MB
    float* sqn = (float*)(wsb + 8388608);       //  128 KB
    float* av  = (float*)(wsb + 8519680);       //  8 MB
    float* bvv = (float*)(wsb + 16908288);      //  8 MB
    int*   knn = (int*)  (wsb + 25296896);      //  2.5 MB
    char*  AHL =         (wsb + 27918336);      //  8 MB f16 hi/lo frag-major
    float* pdg = (float*)(wsb + 36306944);      //  5.24 MB partial dists
    int*   pig = (int*)  (wsb + 41549824);      //  5.24 MB partial ids

    k_transpose<<<512, 256, 0, stream>>>(x, Xt, sqn, AHL);
    k_ab<<<256, 256, 0, stream>>>(Xt, W, av, bvv);
    k_knn<<<1024, 256, 0, stream>>>(AHL, sqn, pdg, pig);
    k_merge<<<256, 128, 0, stream>>>(pdg, pig, knn);
    k_out<<<512, 256, 0, stream>>>(av, bvv, knn, gamma, beta, rmean, rvar, out);
}

// Round 5
// 379.643 us; speedup vs baseline: 2.0536x; 1.0014x over previous
//
#include <hip/hip_runtime.h>

#define B 8
#define C 64
#define N 4096
#define O 64
#define KNN 20
#define PQ 4
#define BN_EPS 1e-5f
#define NEG_SLOPE 0.2f

typedef _Float16 f16x8 __attribute__((ext_vector_type(8)));
typedef float    f32x4 __attribute__((ext_vector_type(4)));
#define MFMA16(a, b, c) __builtin_amdgcn_mfma_f32_16x16x32_f16(a, b, c, 0, 0, 0)

// insert (r,m) into ascending-sorted top-KNN list, dropping old min d[0].
// precondition: r > d[0]. Tie-safe (insert below existing equal value).
// Branch-free parallel form: new_d[j] = med3(d[j], d[j+1], r); depth ~2.
__device__ __forceinline__ void sorted_insert(float (&d)[KNN], int (&id)[KNN],
                                              float r, int m) {
    bool c[KNN];
    #pragma unroll
    for (int j = 0; j < KNN; ++j) c[j] = d[j] < r;
    #pragma unroll
    for (int j = 0; j < KNN - 1; ++j) {
        d[j]  = __builtin_amdgcn_fmed3f(d[j], d[j + 1], r);
        id[j] = c[j + 1] ? id[j + 1] : (c[j] ? m : id[j]);
    }
    d[KNN - 1]  = c[KNN - 1] ? r : d[KNN - 1];
    id[KNN - 1] = c[KNN - 1] ? m : id[KNN - 1];
}

// -------- K0: x (B,C,N) -> Xt (B,N,C) fp32, sq = ||x_n||^2, and AHL: f16 hi/lo
// frag-major: per 16-row group (4096 B): [term][khalf][quad][slot16][8 f16]
__global__ __launch_bounds__(256) void k_transpose(const float* __restrict__ x,
                                                   float* __restrict__ Xt,
                                                   float* __restrict__ sq,
                                                   char* __restrict__ AHL) {
    __shared__ float lds[C][65];
    int b    = blockIdx.x >> 6;
    int n0   = (blockIdx.x & 63) << 6;
    int lane = threadIdx.x & 63;
    int w    = threadIdx.x >> 6;
    #pragma unroll
    for (int i = 0; i < 16; ++i) {
        int c = w * 16 + i;
        lds[c][lane] = x[(size_t)b * C * N + (size_t)c * N + n0 + lane];
    }
    __syncthreads();
    #pragma unroll
    for (int i = 0; i < 16; ++i) {
        int nl = w * 16 + i;
        Xt[(size_t)b * N * C + (size_t)(n0 + nl) * C + lane] = lds[lane][nl];
    }
    // sq via quad-partial reduce: thread t owns n=t>>2, c-range (t&3)*16..+16.
    {
        int n_loc = threadIdx.x >> 2;
        int cg    = threadIdx.x & 3;
        float s = 0.f;
        #pragma unroll
        for (int ii = 0; ii < 16; ++ii) {
            float v = lds[cg * 16 + ii][n_loc];
            s = fmaf(v, v, s);
        }
        s += __shfl_xor(s, 1, 64);
        s += __shfl_xor(s, 2, 64);
        if (cg == 0) sq[b * N + n0 + n_loc] = s;
    }
    int s2  = threadIdx.x & 15;
    int rem = threadIdx.x >> 4;
    int qd  = rem & 3;
    int hh  = (rem >> 2) & 1;
    int tt  = rem >> 3;
    int kb  = hh * 32 + qd * 8;
    for (int i = 0; i < 4; ++i) {
        int rowl = i * 16 + s2;
        f16x8 pk;
        #pragma unroll
        for (int ii = 0; ii < 8; ++ii) {
            float v = lds[kb + ii][rowl];
            _Float16 hv = (_Float16)v;
            if (tt) hv = (_Float16)(v - (float)hv);
            pk[ii] = hv;
        }
        char* dst = AHL + ((size_t)b << 20) + (size_t)((n0 >> 4) + i) * 4096
                  + tt * 2048 + hh * 1024 + qd * 256 + s2 * 16;
        *(f16x8*)dst = pk;
    }
}

// -------- K1: a = X*(W1-W2)^T, bvec = X*W2^T
// b = bid&7: XCD-pinned (bid%8 = XCD round-robin) -> Xt[b] (1 MB) L2-local.
__global__ __launch_bounds__(256, 2) void k_ab(const float* __restrict__ Xt,
                                               const float* __restrict__ W,
                                               float* __restrict__ av,
                                               float* __restrict__ bv) {
    int b  = blockIdx.x & 7;
    int n0 = ((blockIdx.x >> 3) & 31) << 7;
    int o  = threadIdx.x & 63;
    int w  = __builtin_amdgcn_readfirstlane((int)(threadIdx.x >> 6));
    float wa[C], wb[C];
    #pragma unroll
    for (int c = 0; c < C; ++c) {
        float w1 = W[o * 2 * C + c];
        float w2 = W[o * 2 * C + C + c];
        wa[c] = w1 - w2;
        wb[c] = w2;
    }
    const float* xb = Xt + (size_t)b * N * C;
    for (int i = 0; i < 32; ++i) {
        int n = n0 + w * 32 + i;
        const float4* xr4 = (const float4*)(xb + (size_t)n * C);
        float aa = 0.f, bb = 0.f;
        #pragma unroll
        for (int c4 = 0; c4 < C / 4; ++c4) {
            float4 xv = xr4[c4];
            aa = fmaf(xv.x, wa[c4 * 4 + 0], aa);
            bb = fmaf(xv.x, wb[c4 * 4 + 0], bb);
            aa = fmaf(xv.y, wa[c4 * 4 + 1], aa);
            bb = fmaf(xv.y, wb[c4 * 4 + 1], bb);
            aa = fmaf(xv.z, wa[c4 * 4 + 2], aa);
            bb = fmaf(xv.z, wb[c4 * 4 + 2], bb);
            aa = fmaf(xv.w, wa[c4 * 4 + 3], aa);
            bb = fmaf(xv.w, wb[c4 * 4 + 3], bb);
        }
        size_t oidx = ((size_t)b * N + n) * O + o;
        av[oidx] = aa;
        bv[oidx] = bb;
    }
}

// -------- K2: barrier-free streaming MFMA kNN. Zero LDS, zero __syncthreads.
// 4-wave blocks, grid 1024. b = bid&7 (XCD-pinned: 1 MB AHL/XCD), h = bit 3,
// rb = bid>>4. Wave w owns queries rb*64 + w*16..+16; lane quad q scans cand
// slice q. Top-k fully in regs.
//  - warm-fill + one bubble sort; shared quad threshold; med3 insert.
//  - 3-set rotating prefetch (x/y/z): loads for it+3 issued right after the
//    MFMAs of it -> ~2 full iterations of issue->use distance. Tail
//    prefetches clamp to tile 127 (dead redundant load, branch-free).
//    All register sets statically named (rule: no runtime-indexed arrays).
//  - launch_bounds (256,2): do NOT raise the waves hint; a tighter VGPR cap
//    with 3 prefetch sets risks scratch spill (R2: 1 GB WRITE_SIZE).
#define KBODY(A0, A1, A2, A3, SQ4, ITV)                                      \
  {                                                                          \
    const int it_ = (ITV);                                                   \
    f32x4 acc = {0.f, 0.f, 0.f, 0.f};                                        \
    acc = MFMA16(A0, bh0, acc);                                              \
    acc = MFMA16(A1, bh1, acc);                                              \
    acc = MFMA16(A0, bl0, acc);                                              \
    acc = MFMA16(A1, bl1, acc);                                              \
    acc = MFMA16(A2, bh0, acc);                                              \
    acc = MFMA16(A3, bh1, acc);                                              \
    float4 sql = SQ4;                                                        \
    {   /* prefetch it_+3 into this set (clamped at 127) */                  \
        int itn = (it_ + 3 < 127) ? (it_ + 3) : 127;                         \
        const char* p = Asrc + (size_t)itn * 4096 + lane * 16;               \
        A0 = *(const f16x8*)(p);                                             \
        A1 = *(const f16x8*)(p + 1024);                                      \
        A2 = *(const f16x8*)(p + 2048);                                      \
        A3 = *(const f16x8*)(p + 3072);                                      \
        SQ4 = *(const float4*)(sqb + cbase0 + itn * 16 + quad * 4);          \
    }                                                                        \
    int c0 = cbase0 + it_ * 16 + quad * 4;                                   \
    _Pragma("unroll")                                                        \
    for (int r = 0; r < 4; ++r) {                                            \
        float sc = fmaf(2.f, acc[r],                                         \
                        -((r == 0) ? sql.x : (r == 1) ? sql.y                \
                                   : (r == 2) ? sql.z : sql.w));             \
        if (sc > thr) {                                                      \
            _Pragma("unroll")                                                \
            for (int j = 0; j < PQ; ++j) {                                   \
                bool sel = (pc == j);                                        \
                pv[j] = sel ? sc : pv[j];                                    \
                pi[j] = sel ? (c0 + r) : pi[j];                              \
            }                                                                \
            ++pc;                                                            \
        }                                                                    \
        if (__any(pc == PQ)) {                                               \
            _Pragma("unroll")                                                \
            for (int j = 0; j < PQ; ++j)                                     \
                if (j < pc && pv[j] > d[0]) sorted_insert(d, id, pv[j], pi[j]); \
            pc = 0;                                                          \
            float t = d[0];                                                  \
            t = fmaxf(t, __shfl_xor(t, 16, 64));                             \
            t = fmaxf(t, __shfl_xor(t, 32, 64));                             \
            thr = fmaxf(thr, t);                                             \
        }                                                                    \
    }                                                                        \
  }

__global__ __launch_bounds__(256, 2) void k_knn(const char* __restrict__ AHL,
                                                const float* __restrict__ sq,
                                                float* __restrict__ pdg,
                                                int* __restrict__ pig) {
    int bid  = blockIdx.x;
    int rb   = bid >> 4;
    int b    = bid & 7;
    int h    = (bid >> 3) & 1;
    int tid  = threadIdx.x;
    int lane = tid & 63;
    int w    = __builtin_amdgcn_readfirstlane(tid >> 6);
    int quad = lane >> 4;
    const char*  AHLb = AHL + ((size_t)b << 20);
    const float* sqb  = sq + b * N;
    int cbase0 = h * (N / 2);
    const char* Asrc = AHLb + (size_t)cbase0 * 256;

    // B-frags: this wave's query group (rb*4 + w): hi/lo x khalf (16 VGPRs)
    const char* qb = AHLb + (size_t)(rb * 4 + w) * 4096 + lane * 16;
    f16x8 bh0 = *(const f16x8*)(qb);
    f16x8 bh1 = *(const f16x8*)(qb + 1024);
    f16x8 bl0 = *(const f16x8*)(qb + 2048);
    f16x8 bl1 = *(const f16x8*)(qb + 3072);

    float d[KNN]; int id[KNN];
    float pv[PQ]; int pi[PQ]; int pc = 0;
    #pragma unroll
    for (int j = 0; j < PQ; ++j) { pv[j] = 0.f; pi[j] = 0; }

    // prefetch iter 0
    const char* p0 = Asrc + lane * 16;
    f16x8 na0 = *(const f16x8*)(p0);
    f16x8 na1 = *(const f16x8*)(p0 + 1024);
    f16x8 na2 = *(const f16x8*)(p0 + 2048);
    f16x8 na3 = *(const f16x8*)(p0 + 3072);
    float4 nsq = *(const float4*)(sqb + cbase0 + quad * 4);

    // ---- warm-fill: iters 0..4 (20 cands per lane) fill all KNN slots
    #pragma unroll
    for (int it = 0; it < 5; ++it) {
        f16x8 a0 = na0, a1 = na1, a2 = na2, a3 = na3;
        float4 sqv = nsq;
        {
            const char* p = Asrc + (size_t)(it + 1) * 4096 + lane * 16;
            na0 = *(const f16x8*)(p);
            na1 = *(const f16x8*)(p + 1024);
            na2 = *(const f16x8*)(p + 2048);
            na3 = *(const f16x8*)(p + 3072);
            nsq = *(const float4*)(sqb + cbase0 + (it + 1) * 16 + quad * 4);
        }
        f32x4 acc = {0.f, 0.f, 0.f, 0.f};
        acc = MFMA16(a0, bh0, acc);
        acc = MFMA16(a1, bh1, acc);
        acc = MFMA16(a0, bl0, acc);
        acc = MFMA16(a1, bl1, acc);
        acc = MFMA16(a2, bh0, acc);
        acc = MFMA16(a3, bh1, acc);
        int c0 = cbase0 + it * 16 + quad * 4;
        #pragma unroll
        for (int r = 0; r < 4; ++r) {
            float sc = fmaf(2.f, acc[r],
                            -((r == 0) ? sqv.x : (r == 1) ? sqv.y
                                       : (r == 2) ? sqv.z : sqv.w));
            d[it * 4 + r]  = sc;          // compile-time slot index
            id[it * 4 + r] = c0 + r;
        }
    }
    // one-time in-register bubble sort, ascending (compile-time indices)
    #pragma unroll
    for (int i = 0; i < KNN - 1; ++i) {
        #pragma unroll
        for (int j = 0; j < KNN - 1 - i; ++j) {
            bool sw = d[j] > d[j + 1];
            float tv = d[j]; int ti = id[j];
            d[j]      = sw ? d[j + 1] : d[j];
            id[j]     = sw ? id[j + 1] : id[j];
            d[j + 1]  = sw ? tv : d[j + 1];
            id[j + 1] = sw ? ti : id[j + 1];
        }
    }
    // shared threshold across the 4 quad-lanes serving this query
    float thr = d[0];
    thr = fmaxf(thr, __shfl_xor(thr, 16, 64));
    thr = fmaxf(thr, __shfl_xor(thr, 32, 64));

    // ---- 3-set rotating pipeline: x=it5 (from warm-fill prefetch), y=6, z=7
    f16x8 xa0 = na0, xa1 = na1, xa2 = na2, xa3 = na3; float4 xsq = nsq;
    f16x8 ya0, ya1, ya2, ya3; float4 ysq;
    f16x8 za0, za1, za2, za3; float4 zsq;
    {
        const char* p = Asrc + (size_t)6 * 4096 + lane * 16;
        ya0 = *(const f16x8*)(p);
        ya1 = *(const f16x8*)(p + 1024);
        ya2 = *(const f16x8*)(p + 2048);
        ya3 = *(const f16x8*)(p + 3072);
        ysq = *(const float4*)(sqb + cbase0 + 6 * 16 + quad * 4);
    }
    {
        const char* p = Asrc + (size_t)7 * 4096 + lane * 16;
        za0 = *(const f16x8*)(p);
        za1 = *(const f16x8*)(p + 1024);
        za2 = *(const f16x8*)(p + 2048);
        za3 = *(const f16x8*)(p + 3072);
        zsq = *(const float4*)(sqb + cbase0 + 7 * 16 + quad * 4);
    }

    #pragma unroll 1
    for (int g = 0; g < 41; ++g) {             // its 5..127 = 41 * 3
        int itb = 5 + g * 3;
        KBODY(xa0, xa1, xa2, xa3, xsq, itb);
        KBODY(ya0, ya1, ya2, ya3, ysq, itb + 1);
        KBODY(za0, za1, za2, za3, zsq, itb + 2);
    }
    #pragma unroll
    for (int j = 0; j < PQ; ++j)               // final flush
        if (j < pc && pv[j] > d[0]) sorted_insert(d, id, pv[j], pi[j]);

    // in-wave quad-merge tournament via shuffles: 2,3 -> 0,1 then 1 -> 0
    #pragma unroll 1
    for (int step = 0; step < 2; ++step) {
        int off = (step == 0) ? 32 : 16;
        bool active = (step == 0) ? (quad < 2) : (quad == 0);
        for (int j = KNN - 1; j >= 0; --j) {   // descending; early-exit
            float rv = __shfl(d[j], lane + off, 64);
            int   ri = __shfl(id[j], lane + off, 64);
            bool ins = active && (rv > d[0]);
            if (!__any(ins)) break;
            if (ins) sorted_insert(d, id, rv, ri);
        }
    }
    if (lane < 16) {
        size_t rr = (size_t)b * N + rb * 64 + w * 16 + lane;
        float* po = pdg + (rr * 2 + h) * KNN;
        int*   qo = pig + (rr * 2 + h) * KNN;
        #pragma unroll
        for (int j = 0; j < KNN; ++j) { po[j] = d[j]; qo[j] = id[j]; }
    }
}

// -------- K2b: merge the 2 sorted half-lists per query -> knn indices
__global__ __launch_bounds__(128) void k_merge(const float* __restrict__ pdg,
                                               const int* __restrict__ pig,
                                               int* __restrict__ knn) {
    __shared__ float sd[128][41];
    __shared__ int   si[128][41];
    int t = threadIdx.x;
    size_t rr = (size_t)blockIdx.x * 128 + t;
    const float* pr = pdg + rr * (2 * KNN);
    const int*   qr = pig + rr * (2 * KNN);
    #pragma unroll
    for (int j = 0; j < 2 * KNN; ++j) { sd[t][j] = pr[j]; si[t][j] = qr[j]; }
    int i = KNN - 1, j = KNN - 1;
    int* op = knn + rr * KNN;
    for (int o = 0; o < KNN; ++o) {
        bool t0 = (j < 0) || (i >= 0 && sd[t][i] >= sd[t][KNN + j]);
        op[o] = t0 ? si[t][i] : si[t][KNN + j];
        if (t0) --i; else --j;
    }
}

// -------- K3: out[b][o][n] = leaky(scale*(a[n][o] + max_k bvec[idx_k][o]) + bias)
// b = bid&7: XCD-pinned -> each XCD gathers only its own bv[b] (1 MB, L2-res).
__global__ __launch_bounds__(256) void k_out(const float* __restrict__ av,
                                             const float* __restrict__ bv,
                                             const int* __restrict__ knn,
                                             const float* __restrict__ gamma,
                                             const float* __restrict__ beta,
                                             const float* __restrict__ rmean,
                                             const float* __restrict__ rvar,
                                             float* __restrict__ out) {
    __shared__ float lds[64][65];
    int b    = blockIdx.x & 7;
    int n0   = (blockIdx.x >> 3) << 6;
    int lane = threadIdx.x & 63;
    int w    = __builtin_amdgcn_readfirstlane((int)(threadIdx.x >> 6));
    int o    = lane;
    float scale = gamma[o] * rsqrtf(rvar[o] + BN_EPS);
    float bias  = fmaf(-rmean[o], scale, beta[o]);
    const float* bvb = bv + (size_t)b * N * O;
    for (int i = 0; i < 16; ++i) {
        int n = n0 + w * 16 + i;
        const int* kn = knn + ((size_t)b * N + n) * KNN;
        float mx = -3.4e38f, mn = 3.4e38f;
        #pragma unroll
        for (int j = 0; j < KNN; ++j) {
            float v = bvb[(size_t)kn[j] * O + o];
            mx = fmaxf(mx, v);
            mn = fminf(mn, v);
        }
        float a   = av[((size_t)b * N + n) * O + o];
        float sel = (scale >= 0.f) ? (a + mx) : (a + mn);
        float y   = fmaf(sel, scale, bias);
        y = fmaxf(y, NEG_SLOPE * y);
        lds[o][w * 16 + i] = y;
    }
    __syncthreads();
    int r  = threadIdx.x >> 2;
    int c0 = (threadIdx.x & 3) << 4;
    float* ob = out + (size_t)b * O * N + (size_t)r * N + n0;
    #pragma unroll
    for (int j = 0; j < 16; j += 4) {
        float4 v;
        v.x = lds[r][c0 + j + 0];
        v.y = lds[r][c0 + j + 1];
        v.z = lds[r][c0 + j + 2];
        v.w = lds[r][c0 + j + 3];
        *(float4*)(ob + c0 + j) = v;
    }
}

extern "C" void kernel_launch(void* const* d_in, const int* in_sizes, int n_in,
                              void* d_out, int out_size, void* d_ws, size_t ws_size,
                              hipStream_t stream) {
    const float* x     = (const float*)d_in[0];
    const float* W     = (const float*)d_in[1];
    const float* gamma = (const float*)d_in[2];
    const float* beta  = (const float*)d_in[3];
    const float* rmean = (const float*)d_in[4];
    const float* rvar  = (const float*)d_in[5];
    float* out = (float*)d_out;

    char* wsb = (char*)d_ws;
    float* Xt  = (float*)(wsb);                 //  8 MB
    float* sqn = (float*)(wsb + 8388608);       //  128 KB
    float* av  = (float*)(wsb + 8519680);       //  8 MB
    float* bvv = (float*)(wsb + 16908288);      //  8 MB
    int*   knn = (int*)  (wsb + 25296896);      //  2.5 MB
    char*  AHL =         (wsb + 27918336);      //  8 MB f16 hi/lo frag-major
    float* pdg = (float*)(wsb + 36306944);      //  5.24 MB partial dists
    int*   pig = (int*)  (wsb + 41549824);      //  5.24 MB partial ids

    k_transpose<<<512, 256, 0, stream>>>(x, Xt, sqn, AHL);
    k_ab<<<256, 256, 0, stream>>>(Xt, W, av, bvv);
    k_knn<<<1024, 256, 0, stream>>>(AHL, sqn, pdg, pig);
    k_merge<<<256, 128, 0, stream>>>(pdg, pig, knn);
    k_out<<<512, 256, 0, stream>>>(av, bvv, knn, gamma, beta, rmean, rvar, out);
}

// Round 6
// 371.355 us; speedup vs baseline: 2.0994x; 1.0223x over previous
//
#include <hip/hip_runtime.h>

#define B 8
#define C 64
#define N 4096
#define O 64
#define KNN 20
#define PQ 4
#define BN_EPS 1e-5f
#define NEG_SLOPE 0.2f

typedef _Float16 f16x8 __attribute__((ext_vector_type(8)));
typedef float    f32x4 __attribute__((ext_vector_type(4)));
#define MFMA16(a, b, c) __builtin_amdgcn_mfma_f32_16x16x32_f16(a, b, c, 0, 0, 0)

// insert (r,m) into ascending-sorted top-KNN list, dropping old min d[0].
// precondition: r > d[0]. Tie-safe (insert below existing equal value).
// Branch-free parallel form: new_d[j] = med3(d[j], d[j+1], r); depth ~2.
__device__ __forceinline__ void sorted_insert(float (&d)[KNN], int (&id)[KNN],
                                              float r, int m) {
    bool c[KNN];
    #pragma unroll
    for (int j = 0; j < KNN; ++j) c[j] = d[j] < r;
    #pragma unroll
    for (int j = 0; j < KNN - 1; ++j) {
        d[j]  = __builtin_amdgcn_fmed3f(d[j], d[j + 1], r);
        id[j] = c[j + 1] ? id[j + 1] : (c[j] ? m : id[j]);
    }
    d[KNN - 1]  = c[KNN - 1] ? r : d[KNN - 1];
    id[KNN - 1] = c[KNN - 1] ? m : id[KNN - 1];
}

// -------- K0: x (B,C,N) -> Xt (B,N,C) fp32, sq = ||x_n||^2, and AHL: f16 hi/lo
// frag-major: per 16-row group (4096 B): [term][khalf][quad][slot16][8 f16]
__global__ __launch_bounds__(256) void k_transpose(const float* __restrict__ x,
                                                   float* __restrict__ Xt,
                                                   float* __restrict__ sq,
                                                   char* __restrict__ AHL) {
    __shared__ float lds[C][65];
    int b    = blockIdx.x >> 6;
    int n0   = (blockIdx.x & 63) << 6;
    int lane = threadIdx.x & 63;
    int w    = threadIdx.x >> 6;
    #pragma unroll
    for (int i = 0; i < 16; ++i) {
        int c = w * 16 + i;
        lds[c][lane] = x[(size_t)b * C * N + (size_t)c * N + n0 + lane];
    }
    __syncthreads();
    #pragma unroll
    for (int i = 0; i < 16; ++i) {
        int nl = w * 16 + i;
        Xt[(size_t)b * N * C + (size_t)(n0 + nl) * C + lane] = lds[lane][nl];
    }
    // sq via quad-partial reduce: thread t owns n=t>>2, c-range (t&3)*16..+16.
    {
        int n_loc = threadIdx.x >> 2;
        int cg    = threadIdx.x & 3;
        float s = 0.f;
        #pragma unroll
        for (int ii = 0; ii < 16; ++ii) {
            float v = lds[cg * 16 + ii][n_loc];
            s = fmaf(v, v, s);
        }
        s += __shfl_xor(s, 1, 64);
        s += __shfl_xor(s, 2, 64);
        if (cg == 0) sq[b * N + n0 + n_loc] = s;
    }
    int s2  = threadIdx.x & 15;
    int rem = threadIdx.x >> 4;
    int qd  = rem & 3;
    int hh  = (rem >> 2) & 1;
    int tt  = rem >> 3;
    int kb  = hh * 32 + qd * 8;
    for (int i = 0; i < 4; ++i) {
        int rowl = i * 16 + s2;
        f16x8 pk;
        #pragma unroll
        for (int ii = 0; ii < 8; ++ii) {
            float v = lds[kb + ii][rowl];
            _Float16 hv = (_Float16)v;
            if (tt) hv = (_Float16)(v - (float)hv);
            pk[ii] = hv;
        }
        char* dst = AHL + ((size_t)b << 20) + (size_t)((n0 >> 4) + i) * 4096
                  + tt * 2048 + hh * 1024 + qd * 256 + s2 * 16;
        *(f16x8*)dst = pk;
    }
}

// -------- K1: a = X*(W1-W2)^T, bvec = X*W2^T
// b = bid&7: XCD-pinned (bid%8 = XCD round-robin) -> Xt[b] (1 MB) L2-local.
__global__ __launch_bounds__(256, 2) void k_ab(const float* __restrict__ Xt,
                                               const float* __restrict__ W,
                                               float* __restrict__ av,
                                               float* __restrict__ bv) {
    int b  = blockIdx.x & 7;
    int n0 = ((blockIdx.x >> 3) & 31) << 7;
    int o  = threadIdx.x & 63;
    int w  = __builtin_amdgcn_readfirstlane((int)(threadIdx.x >> 6));
    float wa[C], wb[C];
    #pragma unroll
    for (int c = 0; c < C; ++c) {
        float w1 = W[o * 2 * C + c];
        float w2 = W[o * 2 * C + C + c];
        wa[c] = w1 - w2;
        wb[c] = w2;
    }
    const float* xb = Xt + (size_t)b * N * C;
    for (int i = 0; i < 32; ++i) {
        int n = n0 + w * 32 + i;
        const float4* xr4 = (const float4*)(xb + (size_t)n * C);
        float aa = 0.f, bb = 0.f;
        #pragma unroll
        for (int c4 = 0; c4 < C / 4; ++c4) {
            float4 xv = xr4[c4];
            aa = fmaf(xv.x, wa[c4 * 4 + 0], aa);
            bb = fmaf(xv.x, wb[c4 * 4 + 0], bb);
            aa = fmaf(xv.y, wa[c4 * 4 + 1], aa);
            bb = fmaf(xv.y, wb[c4 * 4 + 1], bb);
            aa = fmaf(xv.z, wa[c4 * 4 + 2], aa);
            bb = fmaf(xv.z, wb[c4 * 4 + 2], bb);
            aa = fmaf(xv.w, wa[c4 * 4 + 3], aa);
            bb = fmaf(xv.w, wb[c4 * 4 + 3], bb);
        }
        size_t oidx = ((size_t)b * N + n) * O + o;
        av[oidx] = aa;
        bv[oidx] = bb;
    }
}

// -------- K2: barrier-free streaming MFMA kNN. Zero LDS, zero __syncthreads.
// ONE WAVE PER BLOCK, grid 4096. No intra-block coupling -> CU hosts up to
// ~16 independent waves (vs ~10 with 4-wave blocks), hiding insert-chain
// latency. __launch_bounds__(64,2) keeps VGPR cap >= 256: NO spill (R2's
// (64,4) clamped to 64 VGPR -> d[]/id[] to scratch -> 1 GB WRITE_SIZE.
// Tripwire: WRITE_SIZE must stay ~12288 KB.)
// bid: b = bid&7 (XCD-pinned: each XCD owns one batch, AHL[b] = 1 MB L2-res),
// h = bit3, qg = bid>>4. Wave owns queries qg*16..+16; lane quad scans slice.
//  - warm-fill + one bubble sort; shared quad threshold; med3 insert.
//  - 1-deep prefetch (R5's 3-set rotation regressed: +16 VGPR, more VALU).
__global__ __launch_bounds__(64, 2) void k_knn(const char* __restrict__ AHL,
                                               const float* __restrict__ sq,
                                               float* __restrict__ pdg,
                                               int* __restrict__ pig) {
    int bid  = blockIdx.x;
    int qg   = bid >> 4;
    int b    = bid & 7;
    int h    = (bid >> 3) & 1;
    int lane = threadIdx.x & 63;
    int quad = lane >> 4;
    const char*  AHLb = AHL + ((size_t)b << 20);
    const float* sqb  = sq + b * N;
    int cbase0 = h * (N / 2);
    const char* Asrc = AHLb + (size_t)cbase0 * 256;

    // B-frags: this wave's query group qg: hi/lo x khalf (16 VGPRs)
    const char* qb = AHLb + (size_t)qg * 4096 + lane * 16;
    f16x8 bh0 = *(const f16x8*)(qb);
    f16x8 bh1 = *(const f16x8*)(qb + 1024);
    f16x8 bl0 = *(const f16x8*)(qb + 2048);
    f16x8 bl1 = *(const f16x8*)(qb + 3072);

    float d[KNN]; int id[KNN];
    float pv[PQ]; int pi[PQ]; int pc = 0;
    #pragma unroll
    for (int j = 0; j < PQ; ++j) { pv[j] = 0.f; pi[j] = 0; }

    // prefetch iter 0
    const char* p0 = Asrc + lane * 16;
    f16x8 na0 = *(const f16x8*)(p0);
    f16x8 na1 = *(const f16x8*)(p0 + 1024);
    f16x8 na2 = *(const f16x8*)(p0 + 2048);
    f16x8 na3 = *(const f16x8*)(p0 + 3072);
    float4 nsq = *(const float4*)(sqb + cbase0 + quad * 4);

    // ---- warm-fill: iters 0..4 (20 cands per lane) fill all KNN slots
    #pragma unroll
    for (int it = 0; it < 5; ++it) {
        f16x8 a0 = na0, a1 = na1, a2 = na2, a3 = na3;
        float4 sqv = nsq;
        {
            const char* p = Asrc + (size_t)(it + 1) * 4096 + lane * 16;
            na0 = *(const f16x8*)(p);
            na1 = *(const f16x8*)(p + 1024);
            na2 = *(const f16x8*)(p + 2048);
            na3 = *(const f16x8*)(p + 3072);
            nsq = *(const float4*)(sqb + cbase0 + (it + 1) * 16 + quad * 4);
        }
        f32x4 acc = {0.f, 0.f, 0.f, 0.f};
        acc = MFMA16(a0, bh0, acc);
        acc = MFMA16(a1, bh1, acc);
        acc = MFMA16(a0, bl0, acc);
        acc = MFMA16(a1, bl1, acc);
        acc = MFMA16(a2, bh0, acc);
        acc = MFMA16(a3, bh1, acc);
        int c0 = cbase0 + it * 16 + quad * 4;
        #pragma unroll
        for (int r = 0; r < 4; ++r) {
            float sc = fmaf(2.f, acc[r],
                            -((r == 0) ? sqv.x : (r == 1) ? sqv.y
                                       : (r == 2) ? sqv.z : sqv.w));
            d[it * 4 + r]  = sc;          // compile-time slot index
            id[it * 4 + r] = c0 + r;
        }
    }
    // one-time in-register bubble sort, ascending (compile-time indices)
    #pragma unroll
    for (int i = 0; i < KNN - 1; ++i) {
        #pragma unroll
        for (int j = 0; j < KNN - 1 - i; ++j) {
            bool sw = d[j] > d[j + 1];
            float tv = d[j]; int ti = id[j];
            d[j]      = sw ? d[j + 1] : d[j];
            id[j]     = sw ? id[j + 1] : id[j];
            d[j + 1]  = sw ? tv : d[j + 1];
            id[j + 1] = sw ? ti : id[j + 1];
        }
    }
    // shared threshold across the 4 quad-lanes serving this query
    float thr = d[0];
    thr = fmaxf(thr, __shfl_xor(thr, 16, 64));
    thr = fmaxf(thr, __shfl_xor(thr, 32, 64));

    #pragma unroll 1
    for (int it = 5; it < 128; ++it) {         // 16 cands per iter
        f16x8 a0 = na0, a1 = na1, a2 = na2, a3 = na3;
        float4 sqv = nsq;
        if (it + 1 < 128) {                    // issue next-iter loads early
            const char* p = Asrc + (size_t)(it + 1) * 4096 + lane * 16;
            na0 = *(const f16x8*)(p);
            na1 = *(const f16x8*)(p + 1024);
            na2 = *(const f16x8*)(p + 2048);
            na3 = *(const f16x8*)(p + 3072);
            nsq = *(const float4*)(sqb + cbase0 + (it + 1) * 16 + quad * 4);
        }
        f32x4 acc = {0.f, 0.f, 0.f, 0.f};
        acc = MFMA16(a0, bh0, acc);
        acc = MFMA16(a1, bh1, acc);
        acc = MFMA16(a0, bl0, acc);
        acc = MFMA16(a1, bl1, acc);
        acc = MFMA16(a2, bh0, acc);
        acc = MFMA16(a3, bh1, acc);
        int c0 = cbase0 + it * 16 + quad * 4;  // lane's 4 cands (row=quad*4+r)
        #pragma unroll
        for (int r = 0; r < 4; ++r) {
            float sc = fmaf(2.f, acc[r],
                            -((r == 0) ? sqv.x : (r == 1) ? sqv.y
                                       : (r == 2) ? sqv.z : sqv.w));
            if (sc > thr) {                    // global-ish filter, rare pass
                #pragma unroll
                for (int j = 0; j < PQ; ++j) {
                    bool sel = (pc == j);
                    pv[j] = sel ? sc : pv[j];
                    pi[j] = sel ? (c0 + r) : pi[j];
                }
                ++pc;
            }
            if (__any(pc == PQ)) {             // drain all lanes in parallel
                #pragma unroll
                for (int j = 0; j < PQ; ++j)
                    if (j < pc && pv[j] > d[0]) sorted_insert(d, id, pv[j], pi[j]);
                pc = 0;
                float t = d[0];                // refresh shared threshold
                t = fmaxf(t, __shfl_xor(t, 16, 64));
                t = fmaxf(t, __shfl_xor(t, 32, 64));
                thr = fmaxf(thr, t);
            }
        }
    }
    #pragma unroll
    for (int j = 0; j < PQ; ++j)               // final flush
        if (j < pc && pv[j] > d[0]) sorted_insert(d, id, pv[j], pi[j]);

    // in-wave quad-merge tournament via shuffles: 2,3 -> 0,1 then 1 -> 0
    #pragma unroll 1
    for (int step = 0; step < 2; ++step) {
        int off = (step == 0) ? 32 : 16;
        bool active = (step == 0) ? (quad < 2) : (quad == 0);
        for (int j = KNN - 1; j >= 0; --j) {   // descending; early-exit
            float rv = __shfl(d[j], lane + off, 64);
            int   ri = __shfl(id[j], lane + off, 64);
            bool ins = active && (rv > d[0]);
            if (!__any(ins)) break;
            if (ins) sorted_insert(d, id, rv, ri);
        }
    }
    if (lane < 16) {
        size_t rr = (size_t)b * N + qg * 16 + lane;
        float* po = pdg + (rr * 2 + h) * KNN;
        int*   qo = pig + (rr * 2 + h) * KNN;
        #pragma unroll
        for (int j = 0; j < KNN; ++j) { po[j] = d[j]; qo[j] = id[j]; }
    }
}

// -------- K2b: merge the 2 sorted half-lists per query -> knn indices
__global__ __launch_bounds__(128) void k_merge(const float* __restrict__ pdg,
                                               const int* __restrict__ pig,
                                               int* __restrict__ knn) {
    __shared__ float sd[128][41];
    __shared__ int   si[128][41];
    int t = threadIdx.x;
    size_t rr = (size_t)blockIdx.x * 128 + t;
    const float* pr = pdg + rr * (2 * KNN);
    const int*   qr = pig + rr * (2 * KNN);
    #pragma unroll
    for (int j = 0; j < 2 * KNN; ++j) { sd[t][j] = pr[j]; si[t][j] = qr[j]; }
    int i = KNN - 1, j = KNN - 1;
    int* op = knn + rr * KNN;
    for (int o = 0; o < KNN; ++o) {
        bool t0 = (j < 0) || (i >= 0 && sd[t][i] >= sd[t][KNN + j]);
        op[o] = t0 ? si[t][i] : si[t][KNN + j];
        if (t0) --i; else --j;
    }
}

// -------- K3: out[b][o][n] = leaky(scale*(a[n][o] + max_k bvec[idx_k][o]) + bias)
// b = bid&7: XCD-pinned -> each XCD gathers only its own bv[b] (1 MB, L2-res).
__global__ __launch_bounds__(256) void k_out(const float* __restrict__ av,
                                             const float* __restrict__ bv,
                                             const int* __restrict__ knn,
                                             const float* __restrict__ gamma,
                                             const float* __restrict__ beta,
                                             const float* __restrict__ rmean,
                                             const float* __restrict__ rvar,
                                             float* __restrict__ out) {
    __shared__ float lds[64][65];
    int b    = blockIdx.x & 7;
    int n0   = (blockIdx.x >> 3) << 6;
    int lane = threadIdx.x & 63;
    int w    = __builtin_amdgcn_readfirstlane((int)(threadIdx.x >> 6));
    int o    = lane;
    float scale = gamma[o] * rsqrtf(rvar[o] + BN_EPS);
    float bias  = fmaf(-rmean[o], scale, beta[o]);
    const float* bvb = bv + (size_t)b * N * O;
    for (int i = 0; i < 16; ++i) {
        int n = n0 + w * 16 + i;
        const int* kn = knn + ((size_t)b * N + n) * KNN;
        float mx = -3.4e38f, mn = 3.4e38f;
        #pragma unroll
        for (int j = 0; j < KNN; ++j) {
            float v = bvb[(size_t)kn[j] * O + o];
            mx = fmaxf(mx, v);
            mn = fminf(mn, v);
        }
        float a   = av[((size_t)b * N + n) * O + o];
        float sel = (scale >= 0.f) ? (a + mx) : (a + mn);
        float y   = fmaf(sel, scale, bias);
        y = fmaxf(y, NEG_SLOPE * y);
        lds[o][w * 16 + i] = y;
    }
    __syncthreads();
    int r  = threadIdx.x >> 2;
    int c0 = (threadIdx.x & 3) << 4;
    float* ob = out + (size_t)b * O * N + (size_t)r * N + n0;
    #pragma unroll
    for (int j = 0; j < 16; j += 4) {
        float4 v;
        v.x = lds[r][c0 + j + 0];
        v.y = lds[r][c0 + j + 1];
        v.z = lds[r][c0 + j + 2];
        v.w = lds[r][c0 + j + 3];
        *(float4*)(ob + c0 + j) = v;
    }
}

extern "C" void kernel_launch(void* const* d_in, const int* in_sizes, int n_in,
                              void* d_out, int out_size, void* d_ws, size_t ws_size,
                              hipStream_t stream) {
    const float* x     = (const float*)d_in[0];
    const float* W     = (const float*)d_in[1];
    const float* gamma = (const float*)d_in[2];
    const float* beta  = (const float*)d_in[3];
    const float* rmean = (const float*)d_in[4];
    const float* rvar  = (const float*)d_in[5];
    float* out = (float*)d_out;

    char* wsb = (char*)d_ws;
    float* Xt  = (float*)(wsb);                 //  8 MB
    float* sqn = (float*)(wsb + 8388608);       //  128 KB
    float* av  = (float*)(wsb + 8519680);       //  8 MB
    float* bvv = (float*)(wsb + 16908288);      //  8 MB
    int*   knn = (int*)  (wsb + 25296896);      //  2.5 MB
    char*  AHL =         (wsb + 27918336);      //  8 MB f16 hi/lo frag-major
    float* pdg = (float*)(wsb + 36306944);      //  5.24 MB partial dists
    int*   pig = (int*)  (wsb + 41549824);      //  5.24 MB partial ids

    k_transpose<<<512, 256, 0, stream>>>(x, Xt, sqn, AHL);
    k_ab<<<256, 256, 0, stream>>>(Xt, W, av, bvv);
    k_knn<<<4096, 64, 0, stream>>>(AHL, sqn, pdg, pig);
    k_merge<<<256, 128, 0, stream>>>(pdg, pig, knn);
    k_out<<<512, 256, 0, stream>>>(av, bvv, knn, gamma, beta, rmean, rvar, out);
}